// Round 5
// baseline (135.755 us; speedup 1.0000x reference)
//
#include <hip/hip_runtime.h>

// 14-step recurrence, single persistent kernel, fence-free, NO __syncthreads
// in the step loop.
//   temp = J @ r_{t-1}; U = temp + Iext; sq = (0.2U)^2; s = 0.005*sum(sq); r_t = sq/s
// Carry UNNORMALIZED r̃_t = sq_t and s_t:  J@r_{t-1} = (J@r̃_{t-1})/s_{t-1}.
//
// R5 vs R4:
//  - Per-WAVE barrier: 560 fused {tag:lo32, 0.005*Σsq:hi32} u64 slots per
//    parity; every wave polls all 560 (9 u64 dev-loads/lane) -> s_t falls out
//    of the poll. No LDS, no __syncthreads, no block-level reduce.
//  - 14 write-once r̃ buffers: readers use PLAIN cached loads (no stale-L2
//    possible: first touch is post-flag; kernel-start acquire invalidates
//    across graph replays). Writers write-through (dev-scope) + vmcnt(0).
//  - J rows re-issued per step AFTER arrival, BEFORE poll: 21 L2-hit dwordx4
//    hidden under the barrier wait; __launch_bounds__(256,1) lets the
//    allocator keep them resident anyway.
//  - Tag compare is signed >=  (0xAAAAAAAA poison is negative -> no init).
//    One-barrier-skew proof: a same-parity slot can only hold {old<t+1, t+1}
//    while any wave still polls step t, so payloads read on the successful
//    iteration are exactly step t's.

#define N 1680
#define NV4 420            // N/4
#define NBLK 140
#define BLOCK 256
#define WAVES 4
#define RPW 3              // 140*4*3 = 1680 rows
#define NSTEP 14
#define NSLOT (NBLK * WAVES)   // 560 wave-arrival slots per parity

typedef unsigned long long u64;
typedef unsigned int u32;

__device__ __forceinline__ float wave_reduce(float v) {
    #pragma unroll
    for (int off = 32; off; off >>= 1) v += __shfl_xor(v, off, 64);
    return v;
}
__device__ __forceinline__ void stf_dev(float* p, float v) {
    __hip_atomic_store(p, v, __ATOMIC_RELAXED, __HIP_MEMORY_SCOPE_AGENT);
}
__device__ __forceinline__ u64 ld8_dev(const u64* p) {
    return __hip_atomic_load(p, __ATOMIC_RELAXED, __HIP_MEMORY_SCOPE_AGENT);
}
__device__ __forceinline__ void st8_dev(u64* p, u64 v) {
    __hip_atomic_store(p, v, __ATOMIC_RELAXED, __HIP_MEMORY_SCOPE_AGENT);
}

__global__ __launch_bounds__(BLOCK, 1) void cann_persistent(
    const float* __restrict__ J,
    const float* __restrict__ net_in,      // [0,N): Iext, [N,2N): r0
    float* __restrict__ d_out,             // U(1680) | recSum(1) | r(1680)
    u64* __restrict__ packs,               // 2*NSLOT contiguous u64
    float* __restrict__ rbufs)             // NSTEP * N floats, write-once each
{
    const int tid   = threadIdx.x;
    const int lane  = tid & 63;
    const int wave  = tid >> 6;
    const int gwave = blockIdx.x * WAVES + wave;   // 0..559
    const int row0  = gwave * RPW;

    float iext[RPW];
    #pragma unroll
    for (int r = 0; r < RPW; ++r) iext[r] = net_in[row0 + r];  // wave-uniform bcast

    // prologue: J rows -> regs (cold, HBM/L3)
    float4 Jreg[RPW][7];
    #pragma unroll
    for (int r = 0; r < RPW; ++r) {
        const float4* Jrow = (const float4*)(J + (size_t)(row0 + r) * N);
        #pragma unroll
        for (int k = 0; k < 7; ++k) {
            const int idx = lane + 64 * k;
            Jreg[r][k] = (idx < NV4) ? Jrow[idx] : make_float4(0.f, 0.f, 0.f, 0.f);
        }
    }

    float s_prev = 1.0f;     // step 0 uses raw r0
    float sqv[RPW];          // lane0-valid

    for (int t = 0; t < NSTEP; ++t) {
        // ---- r̃_{t-1}: 7 float4/lane, PLAIN loads (write-once buffer) ----
        const float4* rp = (t == 0) ? (const float4*)(net_in + N)
                                    : (const float4*)(rbufs + (size_t)(t - 1) * N);
        float4 rv[7];
        #pragma unroll
        for (int k = 0; k < 7; ++k) {
            const int idx = lane + 64 * k;
            rv[k] = (idx < NV4) ? rp[idx] : make_float4(0.f, 0.f, 0.f, 0.f);
        }

        // ---- dot(J_row, r̃) from registers; wave shuffle-reduce ----
        float acc[RPW];
        #pragma unroll
        for (int r = 0; r < RPW; ++r) {
            float a = 0.f;
            #pragma unroll
            for (int k = 0; k < 7; ++k) {
                const float4 j4 = Jreg[r][k], r4 = rv[k];
                a += j4.x * r4.x + j4.y * r4.y + j4.z * r4.z + j4.w * r4.w;
            }
            acc[r] = wave_reduce(a);
        }

        // ---- lane0: U, sq; write-through sq to rbufs[t] ----
        float psum = 0.f;
        if (lane == 0) {
            float* rd = rbufs + (size_t)t * N;
            #pragma unroll
            for (int r = 0; r < RPW; ++r) {
                const float U  = acc[r] / s_prev + iext[r];    // ALPHA=BETA=1
                const float u2 = 0.2f * U;
                const float sq = u2 * u2;
                sqv[r] = sq;
                psum  += sq;
                stf_dev(&rd[row0 + r], sq);
                if (t == NSTEP - 1) d_out[row0 + r] = U;       // U_13 (plain)
            }
        }
        asm volatile("s_waitcnt vmcnt(0)" ::: "memory");        // sq at L3

        // ---- arrival: fused {tag, wave partial} ----
        u64* pk = packs + (size_t)(t & 1) * NSLOT;
        if (lane == 0)
            st8_dev(&pk[gwave],
                    (u64)(u32)(t + 1) | ((u64)__float_as_uint(0.005f * psum) << 32));

        // ---- J refresh for next step: L2 hits, hidden under the poll ----
        if (t < NSTEP - 1) {
            #pragma unroll
            for (int r = 0; r < RPW; ++r) {
                const float4* Jrow = (const float4*)(J + (size_t)(row0 + r) * N);
                #pragma unroll
                for (int k = 0; k < 7; ++k) {
                    const int idx = lane + 64 * k;
                    if (idx < NV4) Jreg[r][k] = Jrow[idx];
                }
            }
        }

        // ---- poll all 560 slots; payload sum of the final iteration = s_t ----
        const int tgt = t + 1;
        float sv;
        for (;;) {
            bool ok = true;
            sv = 0.f;
            #pragma unroll
            for (int j = 0; j < 9; ++j) {
                const int idx = lane + 64 * j;
                if (j < 8 || lane < NSLOT - 512) {     // idx < 560
                    const u64 f = ld8_dev(&pk[idx]);
                    ok = ok && ((int)(u32)f >= tgt);   // poison-negative-proof
                    sv += __uint_as_float((u32)(f >> 32));
                }
            }
            if (__all(ok)) break;
            __builtin_amdgcn_s_sleep(1);
        }
        asm volatile("" ::: "memory");                  // no hoisting past the poll
        s_prev = wave_reduce(sv);                       // s_t, wave-uniform
    }

    // ---- epilogue: s_prev == recSum_13 ----
    if (lane == 0) {
        if (gwave == 0) d_out[N] = s_prev;              // recSum_13
        #pragma unroll
        for (int r = 0; r < RPW; ++r)
            d_out[N + 1 + row0 + r] = sqv[r] / s_prev;  // r_13
    }
}

extern "C" void kernel_launch(void* const* d_in, const int* in_sizes, int n_in,
                              void* d_out, int out_size, void* d_ws, size_t ws_size,
                              hipStream_t stream) {
    const float* net_in = (const float*)d_in[0];
    const float* J      = (const float*)d_in[1];
    float* out = (float*)d_out;

    // ws layout: packs @0 (2*560 u64 = 8960 B), rbufs @8960 (14*1680 floats)
    u64*   packs = (u64*)d_ws;
    float* rbufs = (float*)((char*)d_ws + 2 * NSLOT * sizeof(u64));

    cann_persistent<<<NBLK, BLOCK, 0, stream>>>(J, net_in, out, packs, rbufs);
}